// Round 1
// baseline (296.540 us; speedup 1.0000x reference)
//
#include <hip/hip_runtime.h>
#include <hip/hip_fp16.h>

// Block-diagonal equivariant linear: out[n, o, m](l) = sum_i W_l[o,i,m] * x_l[n,i,m]
// N nodes, MULT=32, l in {0,1,2,3}, m_l = 2l+1, out row = 512 f32.
//
// Design: memory-bound (1.07 GB @ ~6.3 TB/s => ~170us floor).
//  - stage x tile (32 nodes) transposed into LDS as f16 planes [i][plane][node]
//  - stage W once per block as f16 planes [i][plane][o]
//  - thread = (plane(l,mi), ntile, otile): 8 nodes x 8 outs, v_fma_mix_f32 (f16xf16+f32)
//  - outputs transposed back through LDS, stored as coalesced float4
// LDS: XT 32KB + WT 32KB = 64KB -> 2 blocks/CU. Plane layout i-major => <=2-way bank conflicts.

#define TN  32
#define NTH 256

#define FMA_MIX(a, x, w, SX, SW) \
  asm("v_fma_mix_f32 %0, %1, %2, %0 op_sel:[" SX "," SW ",0] op_sel_hi:[1,1,0]" \
      : "+v"(a) : "v"(x), "v"(w))

// Stage 32 rows x (32*M_) f32 from src into f16 planes:
// element e = row*(32*M_) + i*M_ + mi  ->  dst[i*512 + (PB+mi)*32 + row]
template<int M_, int PB>
__device__ __forceinline__ void stage_tile(const float* __restrict__ src,
                                           __half* __restrict__ dst, int tid)
{
    #pragma unroll
    for (int it = 0; it < M_; ++it) {
        const int f = tid + it * NTH;              // float4 index; 256*M_ total
        float4 v = ((const float4*)src)[f];
        const int e0 = 4 * f;
        const float* vf = (const float*)&v;
        #pragma unroll
        for (int k = 0; k < 4; ++k) {
            const int e   = e0 + k;
            const int row = e / (32 * M_);
            const int r   = e - row * (32 * M_);
            const int i   = r / M_;
            const int mi  = r - i * M_;
            dst[i * 512 + (PB + mi) * 32 + row] = __float2half(vf[k]);
        }
    }
}

__global__ __launch_bounds__(NTH, 2) void eqlin(
    const float* __restrict__ x0, const float* __restrict__ x1,
    const float* __restrict__ x2, const float* __restrict__ x3,
    const float* __restrict__ w0, const float* __restrict__ w1,
    const float* __restrict__ w2, const float* __restrict__ w3,
    float* __restrict__ out, int n_tiles)
{
    __shared__ __align__(16) __half XT[16384];   // 32KB: x planes / reused as OUT
    __shared__ __align__(16) __half WT[16384];   // 32KB: weight planes
    const int tid = threadIdx.x;

    // ---- stage W once per block (planes: l0->0, l1->1..3, l2->4..8, l3->9..15)
    stage_tile<1, 0>(w0, WT, tid);
    stage_tile<3, 1>(w1, WT, tid);
    stage_tile<5, 4>(w2, WT, tid);
    stage_tile<7, 9>(w3, WT, tid);

    // ---- thread task: plane g, node-tile nt (8 nodes), o-tile ot (8 outputs)
    const int g  = tid >> 4;         // 0..15 == plane index
    const int nt = (tid >> 2) & 3;
    const int ot = tid & 3;
    int L, MI;
    if (g == 0)     { L = 0; MI = 0;     }
    else if (g < 4) { L = 1; MI = g - 1; }
    else if (g < 9) { L = 2; MI = g - 4; }
    else            { L = 3; MI = g - 9; }
    const int Mm   = 2 * L + 1;
    const int BASE = (L == 0) ? 0 : (L == 1) ? 32 : (L == 2) ? 128 : 288;

    for (int t = blockIdx.x; t < n_tiles; t += gridDim.x) {
        const long node0 = (long)t * TN;
        __syncthreads();                         // prev tile's OUT fully consumed
        stage_tile<1, 0>(x0 + node0 * 32,  XT, tid);
        stage_tile<3, 1>(x1 + node0 * 96,  XT, tid);
        stage_tile<5, 4>(x2 + node0 * 160, XT, tid);
        stage_tile<7, 9>(x3 + node0 * 224, XT, tid);
        __syncthreads();

        // ---- compute: acc[8 nodes][8 outs], K=32
        float acc[8][8] = {};
        const __half* xp = XT + g * 32 + nt * 8;
        const __half* wp = WT + g * 32 + ot * 8;
        #pragma unroll 4
        for (int i = 0; i < 32; ++i) {
            uint4 xv = *(const uint4*)(xp + i * 512);
            uint4 wv = *(const uint4*)(wp + i * 512);
            unsigned xa[4] = {xv.x, xv.y, xv.z, xv.w};
            unsigned wa[4] = {wv.x, wv.y, wv.z, wv.w};
            #pragma unroll
            for (int a2 = 0; a2 < 4; ++a2) {
                #pragma unroll
                for (int b2 = 0; b2 < 4; ++b2) {
                    FMA_MIX(acc[2*a2  ][2*b2  ], xa[a2], wa[b2], "0", "0");
                    FMA_MIX(acc[2*a2+1][2*b2  ], xa[a2], wa[b2], "1", "0");
                    FMA_MIX(acc[2*a2  ][2*b2+1], xa[a2], wa[b2], "0", "1");
                    FMA_MIX(acc[2*a2+1][2*b2+1], xa[a2], wa[b2], "1", "1");
                }
            }
        }
        __syncthreads();                         // all XT reads done

        // ---- transpose out through LDS (f16), col = BASE + o*Mm + MI
        __half* OUT = XT;
        #pragma unroll
        for (int nn = 0; nn < 8; ++nn) {
            const int node = nt * 8 + nn;
            #pragma unroll
            for (int oo = 0; oo < 8; ++oo) {
                const int col = BASE + (ot * 8 + oo) * Mm + MI;
                OUT[node * 512 + col] = __float2half(acc[nn][oo]);
            }
        }
        __syncthreads();

        // ---- coalesced store: tile slice is contiguous 32*512 f32
        float* dst = out + node0 * 512;
        #pragma unroll
        for (int it = 0; it < 8; ++it) {
            const int e = (tid + it * NTH) * 8;
            uint4 v = *(const uint4*)(OUT + e);
            const __half2* hv = (const __half2*)&v;
            float2 f0 = __half22float2(hv[0]);
            float2 f1 = __half22float2(hv[1]);
            float2 f2 = __half22float2(hv[2]);
            float2 f3 = __half22float2(hv[3]);
            float4 o0 = make_float4(f0.x, f0.y, f1.x, f1.y);
            float4 o1 = make_float4(f2.x, f2.y, f3.x, f3.y);
            *(float4*)(dst + e)     = o0;
            *(float4*)(dst + e + 4) = o1;
        }
    }
}

extern "C" void kernel_launch(void* const* d_in, const int* in_sizes, int n_in,
                              void* d_out, int out_size, void* d_ws, size_t ws_size,
                              hipStream_t stream)
{
    // Identify pointers robustly by size: x_l = N*32*m, W_l = 1024*m, m in {1,3,5,7}
    long tot = 0;
    for (int i = 0; i < n_in; ++i) tot += in_sizes[i];
    const long N = (tot - 16384) / 512;
    const int  ms[4] = {1, 3, 5, 7};
    const float* xs[4]  = {nullptr, nullptr, nullptr, nullptr};
    const float* wsp[4] = {nullptr, nullptr, nullptr, nullptr};
    for (int i = 0; i < n_in; ++i) {
        const long s = in_sizes[i];
        for (int l = 0; l < 4; ++l) {
            if (s == N * 32 * ms[l])      xs[l]  = (const float*)d_in[i];
            else if (s == 1024L * ms[l])  wsp[l] = (const float*)d_in[i];
        }
    }
    const int n_tiles = (int)(N / TN);
    const int grid = 512;                        // 2 blocks/CU (LDS-limited), persistent
    hipLaunchKernelGGL(eqlin, dim3(grid), dim3(NTH), 0, stream,
                       xs[0], xs[1], xs[2], xs[3],
                       wsp[0], wsp[1], wsp[2], wsp[3],
                       (float*)d_out, n_tiles);
}

// Round 2
// 231.567 us; speedup vs baseline: 1.2806x; 1.2806x over previous
//
#include <hip/hip_runtime.h>
#include <hip/hip_fp16.h>

// out[n,o,m](l) = sum_i W_l[o,i,m] * x_l[n,i,m];  N=262144, MULT=32, m_l in {1,3,5,7}.
// Memory-bound: 1.07GB @ ~6.3TB/s => ~170us floor.
//
// Round-2 structure (fixes round-1's 16-way staging bank conflicts + low occupancy):
//  - LDS layout [plane][node|o][i] f16, i contiguous, node-stride 40 halves (80B),
//    plane-stride 1280 halves. i enters the bank index directly -> staging writes
//    spread across banks; fragment reads are ds_read_b128, bank-even per quarter-wave.
//  - Compute via mfma_f32_16x16x32_f16: per plane, C[32x32] = X[32x32] * W^T-frag,
//    4 MFMA total (K=32 in one instr). 8 waves x 2 planes each.
//  - C -> f16 LDS overlay (node-stride 520, 16B-aligned) -> coalesced float4 stores.
//  - 512 thr/block, XT+WT = 80KB LDS -> 2 blocks/CU = 16 waves/CU.

#define NTH 512
#define TN  32

typedef _Float16 f16x8 __attribute__((ext_vector_type(8)));
typedef float    f32x4 __attribute__((ext_vector_type(4)));

// src element e = node*(32*M_) + i*M_ + mi   ->   dst[(PB+mi)*1280 + node*40 + i]
template<int M_, int PB>
__device__ __forceinline__ void stage(const float* __restrict__ src,
                                      __half* __restrict__ dst, int tid)
{
    #pragma unroll
    for (int it = 0; it < (256 * M_ + NTH - 1) / NTH; ++it) {
        const int f = tid + it * NTH;
        if (f < 256 * M_) {
            float4 v = ((const float4*)src)[f];
            const int e0 = 4 * f;
            if (M_ == 1) {
                // 4 consecutive i, same node: b64 write
                const int node = e0 >> 5, i = e0 & 31;
                __half2* p = (__half2*)(dst + node * 40 + i);
                p[0] = __floats2half2_rn(v.x, v.y);
                p[1] = __floats2half2_rn(v.z, v.w);
            } else {
                const float vf[4] = {v.x, v.y, v.z, v.w};
                #pragma unroll
                for (int k = 0; k < 4; ++k) {
                    const int e    = e0 + k;
                    const int node = e / (32 * M_);
                    const int r    = e - node * (32 * M_);
                    const int i    = r / M_, mi = r - i * M_;
                    dst[(PB + mi) * 1280 + node * 40 + i] = __float2half(vf[k]);
                }
            }
        }
    }
}

__device__ __forceinline__ void plane_info(int p, int& Mm, int& BASE, int& MI)
{
    if (p == 0)     { Mm = 1; BASE = 0;   MI = 0;     }
    else if (p < 4) { Mm = 3; BASE = 32;  MI = p - 1; }
    else if (p < 9) { Mm = 5; BASE = 128; MI = p - 4; }
    else            { Mm = 7; BASE = 288; MI = p - 9; }
}

__global__ __launch_bounds__(NTH, 4) void eqlin(
    const float* __restrict__ x0, const float* __restrict__ x1,
    const float* __restrict__ x2, const float* __restrict__ x3,
    const float* __restrict__ w0, const float* __restrict__ w1,
    const float* __restrict__ w2, const float* __restrict__ w3,
    float* __restrict__ out, int n_tiles)
{
    __shared__ __align__(16) __half XT[20480];   // 40KB: x planes / OUT overlay
    __shared__ __align__(16) __half WT[20480];   // 40KB: W planes
    const int tid  = threadIdx.x;
    const int wave = tid >> 6;
    const int lane = tid & 63;

    // W staged once per block (W_l[o,i,mi]: same element order as x, node->o)
    stage<1, 0>(w0, WT, tid);
    stage<3, 1>(w1, WT, tid);
    stage<5, 4>(w2, WT, tid);
    stage<7, 9>(w3, WT, tid);

    // per-wave plane constants (planes 2w, 2w+1)
    int Mm0, BASE0, MI0, Mm1, BASE1, MI1;
    plane_info(wave * 2,     Mm0, BASE0, MI0);
    plane_info(wave * 2 + 1, Mm1, BASE1, MI1);

    const int lrow = lane & 15;          // A row / B col / C col
    const int lk8  = (lane >> 4) * 8;    // k-chunk offset (halves)
    const int crow = (lane >> 4) * 4;    // C row base

    for (int t = blockIdx.x; t < n_tiles; t += gridDim.x) {
        const long node0 = (long)t * TN;
        __syncthreads();                               // OUT reads of prev tile done
        stage<1, 0>(x0 + node0 * 32,  XT, tid);
        stage<3, 1>(x1 + node0 * 96,  XT, tid);
        stage<5, 4>(x2 + node0 * 160, XT, tid);
        stage<7, 9>(x3 + node0 * 224, XT, tid);
        __syncthreads();

        f32x4 acc[2][2][2] = {};   // [pl][nh][oh]
        #pragma unroll
        for (int pl = 0; pl < 2; ++pl) {
            const int plane = wave * 2 + pl;
            const __half* xb = XT + plane * 1280 + lrow * 40 + lk8;
            const __half* wb = WT + plane * 1280 + lrow * 40 + lk8;
            f16x8 A0 = *(const f16x8*)xb;
            f16x8 A1 = *(const f16x8*)(xb + 640);      // +16 nodes
            f16x8 B0 = *(const f16x8*)wb;
            f16x8 B1 = *(const f16x8*)(wb + 640);      // +16 outs
            acc[pl][0][0] = __builtin_amdgcn_mfma_f32_16x16x32_f16(A0, B0, acc[pl][0][0], 0, 0, 0);
            acc[pl][0][1] = __builtin_amdgcn_mfma_f32_16x16x32_f16(A0, B1, acc[pl][0][1], 0, 0, 0);
            acc[pl][1][0] = __builtin_amdgcn_mfma_f32_16x16x32_f16(A1, B0, acc[pl][1][0], 0, 0, 0);
            acc[pl][1][1] = __builtin_amdgcn_mfma_f32_16x16x32_f16(A1, B1, acc[pl][1][1], 0, 0, 0);
        }
        __syncthreads();                               // XT reads done before overlay

        // C -> OUT (f16), node-stride 520 halves (1040B: 16B-aligned, bank-spread)
        __half* OUT = XT;
        #pragma unroll
        for (int pl = 0; pl < 2; ++pl) {
            const int Mm   = pl ? Mm1   : Mm0;
            const int BASE = pl ? BASE1 : BASE0;
            const int MI   = pl ? MI1   : MI0;
            #pragma unroll
            for (int nh = 0; nh < 2; ++nh)
            #pragma unroll
            for (int oh = 0; oh < 2; ++oh) {
                const int o     = oh * 16 + lrow;
                const int colb  = BASE + o * Mm + MI;
                const int nodeb = nh * 16 + crow;
                #pragma unroll
                for (int r = 0; r < 4; ++r)
                    OUT[(nodeb + r) * 520 + colb] = __float2half(acc[pl][nh][oh][r]);
            }
        }
        __syncthreads();

        // OUT -> global, coalesced float4
        float* dst = out + node0 * 512;
        #pragma unroll
        for (int it = 0; it < 4; ++it) {
            const int d0   = 8 * tid + 4096 * it;
            const int node = d0 >> 9, col = d0 & 511;
            uint4 h8 = *(const uint4*)(OUT + node * 520 + col);   // 16B-aligned
            const __half2* hp = (const __half2*)&h8;
            float2 f0 = __half22float2(hp[0]);
            float2 f1 = __half22float2(hp[1]);
            float2 f2 = __half22float2(hp[2]);
            float2 f3 = __half22float2(hp[3]);
            *(float4*)(dst + d0)     = make_float4(f0.x, f0.y, f1.x, f1.y);
            *(float4*)(dst + d0 + 4) = make_float4(f2.x, f2.y, f3.x, f3.y);
        }
    }
}

extern "C" void kernel_launch(void* const* d_in, const int* in_sizes, int n_in,
                              void* d_out, int out_size, void* d_ws, size_t ws_size,
                              hipStream_t stream)
{
    // Identify pointers by size: x_l = N*32*m, W_l = 1024*m, m in {1,3,5,7}
    long tot = 0;
    for (int i = 0; i < n_in; ++i) tot += in_sizes[i];
    const long N = (tot - 16384) / 512;
    const int  ms[4] = {1, 3, 5, 7};
    const float* xs[4]  = {nullptr, nullptr, nullptr, nullptr};
    const float* wsp[4] = {nullptr, nullptr, nullptr, nullptr};
    for (int i = 0; i < n_in; ++i) {
        const long s = in_sizes[i];
        for (int l = 0; l < 4; ++l) {
            if (s == N * 32 * ms[l])      xs[l]  = (const float*)d_in[i];
            else if (s == 1024L * ms[l])  wsp[l] = (const float*)d_in[i];
        }
    }
    const int n_tiles = (int)(N / TN);
    const int grid = 512;                 // 2 blocks/CU, persistent (16 tiles each)
    hipLaunchKernelGGL(eqlin, dim3(grid), dim3(NTH), 0, stream,
                       xs[0], xs[1], xs[2], xs[3],
                       wsp[0], wsp[1], wsp[2], wsp[3],
                       (float*)d_out, n_tiles);
}

// Round 3
// 217.050 us; speedup vs baseline: 1.3662x; 1.0669x over previous
//
#include <hip/hip_runtime.h>
#include <hip/hip_fp16.h>

// out[n,o,m](l) = sum_i W_l[o,i,m] * x_l[n,i,m];  N=262144, MULT=32, m_l in {1,3,5,7}.
// Memory-bound: 1.07GB @ ~6.3TB/s => ~170us floor.
//
// Round-3: round-2 MFMA structure + software pipeline:
//  - raw barriers (lgkmcnt(0) only, NO vmcnt drain) so global loads/stores
//    stay in flight across all 4 per-tile barriers (m201 pattern)
//  - T14 register prefetch: tile t+1's x loaded into 8xfloat4 regs during
//    tile t's compute/store phases
//  - per-irrep thread grouping for staging: LDS scatter offsets are per-thread
//    constants (j-step = +4 nodes = +160 halves), no div/mod in the loop
// LDS [plane][node|o][i] f16, node-stride 40 halves; XT+WT = 80KB -> 2 blocks/CU.

#define NTH 512
#define TN  32

typedef _Float16 f16x8 __attribute__((ext_vector_type(8)));
typedef float    f32x4 __attribute__((ext_vector_type(4)));

// LDS-only barrier: order ds ops, leave vmem in flight.
#define LGKM0_BAR() do { asm volatile("s_waitcnt lgkmcnt(0)" ::: "memory"); \
                         __builtin_amdgcn_s_barrier(); } while (0)

// Generic (slow, once-per-kernel) stage for W: element e = o*(32*M_) + i*M_ + mi
//   -> dst[(PB+mi)*1280 + o*40 + i]
template<int M_, int PB>
__device__ __forceinline__ void stageW(const float* __restrict__ src,
                                       __half* __restrict__ dst, int tid)
{
    #pragma unroll
    for (int it = 0; it < (256 * M_ + NTH - 1) / NTH; ++it) {
        const int f = tid + it * NTH;
        if (f < 256 * M_) {
            float4 v = ((const float4*)src)[f];
            const float vf[4] = {v.x, v.y, v.z, v.w};
            const int e0 = 4 * f;
            #pragma unroll
            for (int k = 0; k < 4; ++k) {
                const int e = e0 + k;
                const int o = e / (32 * M_);
                const int r = e - o * (32 * M_);
                const int i = r / M_, mi = r - i * M_;
                dst[(PB + mi) * 1280 + o * 40 + i] = __float2half(vf[k]);
            }
        }
    }
}

template<int M_, int PB>
__device__ __forceinline__ void mkoff(int tloc, int* offk)
{
    const int e0    = 4 * tloc;
    const int nodel = e0 / (32 * M_);
    const int r0    = e0 - nodel * (32 * M_);
    #pragma unroll
    for (int k = 0; k < 4; ++k) {
        const int ii = (r0 + k) / M_, mi = (r0 + k) - ii * M_;
        offk[k] = (PB + mi) * 1280 + nodel * 40 + ii;
    }
}

__device__ __forceinline__ void plane_info(int p, int& Mm, int& BASE, int& MI)
{
    if (p == 0)     { Mm = 1; BASE = 0;   MI = 0;     }
    else if (p < 4) { Mm = 3; BASE = 32;  MI = p - 1; }
    else if (p < 9) { Mm = 5; BASE = 128; MI = p - 4; }
    else            { Mm = 7; BASE = 288; MI = p - 9; }
}

__global__ __launch_bounds__(NTH, 4) void eqlin(
    const float* __restrict__ x0, const float* __restrict__ x1,
    const float* __restrict__ x2, const float* __restrict__ x3,
    const float* __restrict__ w0, const float* __restrict__ w1,
    const float* __restrict__ w2, const float* __restrict__ w3,
    float* __restrict__ out, int n_tiles)
{
    __shared__ __align__(16) __half XT[20480];   // 40KB: x planes / OUT overlay
    __shared__ __align__(16) __half WT[20480];   // 40KB: W planes
    const int tid  = threadIdx.x;
    const int wave = tid >> 6;
    const int lane = tid & 63;

    // ---- per-thread staging group: threads [0,32) -> x0, [32,128) -> x1,
    //      [128,288) -> x2, [288,512) -> x3; within group f = tloc + j*thrg.
    int thrg, Mg, offk[4];
    const float* xb;
    bool isM1 = false;
    if (tid < 32)       { thrg = 32;  Mg = 1; xb = x0; mkoff<1, 0>(tid,       offk); isM1 = true; }
    else if (tid < 128) { thrg = 96;  Mg = 3; xb = x1; mkoff<3, 1>(tid - 32,  offk); }
    else if (tid < 288) { thrg = 160; Mg = 5; xb = x2; mkoff<5, 4>(tid - 128, offk); }
    else                { thrg = 224; Mg = 7; xb = x3; mkoff<7, 9>(tid - 288, offk); }
    const int  tloc    = (tid < 32) ? tid : (tid < 128) ? tid - 32 : (tid < 288) ? tid - 128 : tid - 288;
    const long jstride = 4L * thrg;                       // floats between j's
    const long tstride = (long)gridDim.x * 1024L * Mg;    // floats between my tiles

    // ---- prologue: issue prefetch for tile blockIdx.x immediately
    const float* srcp = xb + (long)blockIdx.x * (1024L * Mg) + 4 * tloc;
    float4 pf[8];
    #pragma unroll
    for (int j = 0; j < 8; ++j)
        pf[j] = *(const float4*)(srcp + j * jstride);

    // ---- stage W once (overlaps prefetch latency)
    stageW<1, 0>(w0, WT, tid);
    stageW<3, 1>(w1, WT, tid);
    stageW<5, 4>(w2, WT, tid);
    stageW<7, 9>(w3, WT, tid);

    // ---- per-wave plane constants (planes 2w, 2w+1)
    int Mm0, BASE0, MI0, Mm1, BASE1, MI1;
    plane_info(wave * 2,     Mm0, BASE0, MI0);
    plane_info(wave * 2 + 1, Mm1, BASE1, MI1);
    const int lrow = lane & 15;          // A row / B col / C col
    const int lk8  = (lane >> 4) * 8;    // k-chunk offset (halves)
    const int crow = (lane >> 4) * 4;    // C row base

    for (int t = blockIdx.x; t < n_tiles; t += gridDim.x) {
        const long node0 = (long)t * TN;

        LGKM0_BAR();                     // prev tile's overlay reads done; XT free

        // ---- stage x tile t from prefetch regs (cvt f32->f16, scatter writes)
        #pragma unroll
        for (int j = 0; j < 8; ++j) {
            const float4 v = pf[j];
            const int jb = j * 160;      // +4 nodes per j
            if (isM1) {
                __half2* p = (__half2*)&XT[offk[0] + jb];
                p[0] = __floats2half2_rn(v.x, v.y);
                p[1] = __floats2half2_rn(v.z, v.w);
            } else {
                XT[offk[0] + jb] = __float2half(v.x);
                XT[offk[1] + jb] = __float2half(v.y);
                XT[offk[2] + jb] = __float2half(v.z);
                XT[offk[3] + jb] = __float2half(v.w);
            }
        }

        // ---- issue prefetch for tile t+gridDim.x (hidden under MFMA+store)
        if (t + (long)gridDim.x < n_tiles) {
            srcp += tstride;
            #pragma unroll
            for (int j = 0; j < 8; ++j)
                pf[j] = *(const float4*)(srcp + j * jstride);
        }

        LGKM0_BAR();                     // XT staged

        // ---- MFMA: per plane C[32n x 32o] = X * W, K=32 in one instruction
        f32x4 acc[2][2][2] = {};         // [pl][nh][oh]
        #pragma unroll
        for (int pl = 0; pl < 2; ++pl) {
            const int plane = wave * 2 + pl;
            const __half* xp = XT + plane * 1280 + lrow * 40 + lk8;
            const __half* wp = WT + plane * 1280 + lrow * 40 + lk8;
            f16x8 A0 = *(const f16x8*)xp;
            f16x8 A1 = *(const f16x8*)(xp + 640);      // +16 nodes
            f16x8 B0 = *(const f16x8*)wp;
            f16x8 B1 = *(const f16x8*)(wp + 640);      // +16 outs
            acc[pl][0][0] = __builtin_amdgcn_mfma_f32_16x16x32_f16(A0, B0, acc[pl][0][0], 0, 0, 0);
            acc[pl][0][1] = __builtin_amdgcn_mfma_f32_16x16x32_f16(A0, B1, acc[pl][0][1], 0, 0, 0);
            acc[pl][1][0] = __builtin_amdgcn_mfma_f32_16x16x32_f16(A1, B0, acc[pl][1][0], 0, 0, 0);
            acc[pl][1][1] = __builtin_amdgcn_mfma_f32_16x16x32_f16(A1, B1, acc[pl][1][1], 0, 0, 0);
        }

        LGKM0_BAR();                     // all XT fragment reads done

        // ---- C -> OUT overlay (f16), node-stride 520 halves (16B-aligned)
        __half* OUT = XT;
        #pragma unroll
        for (int pl = 0; pl < 2; ++pl) {
            const int Mm   = pl ? Mm1   : Mm0;
            const int BASE = pl ? BASE1 : BASE0;
            const int MI   = pl ? MI1   : MI0;
            #pragma unroll
            for (int nh = 0; nh < 2; ++nh)
            #pragma unroll
            for (int oh = 0; oh < 2; ++oh) {
                const int o     = oh * 16 + lrow;
                const int colb  = BASE + o * Mm + MI;
                const int nodeb = nh * 16 + crow;
                #pragma unroll
                for (int r = 0; r < 4; ++r)
                    OUT[(nodeb + r) * 520 + colb] = __float2half(acc[pl][nh][oh][r]);
            }
        }

        LGKM0_BAR();                     // overlay visible

        // ---- OUT -> global, coalesced float4 (stores left in flight)
        float* dst = out + node0 * 512;
        #pragma unroll
        for (int it = 0; it < 4; ++it) {
            const int d0   = 8 * tid + 4096 * it;
            const int node = d0 >> 9, col = d0 & 511;
            uint4 h8 = *(const uint4*)(OUT + node * 520 + col);
            const __half2* hp = (const __half2*)&h8;
            float2 f0 = __half22float2(hp[0]);
            float2 f1 = __half22float2(hp[1]);
            float2 f2 = __half22float2(hp[2]);
            float2 f3 = __half22float2(hp[3]);
            *(float4*)(dst + d0)     = make_float4(f0.x, f0.y, f1.x, f1.y);
            *(float4*)(dst + d0 + 4) = make_float4(f2.x, f2.y, f3.x, f3.y);
        }
    }
}

extern "C" void kernel_launch(void* const* d_in, const int* in_sizes, int n_in,
                              void* d_out, int out_size, void* d_ws, size_t ws_size,
                              hipStream_t stream)
{
    // Identify pointers by size: x_l = N*32*m, W_l = 1024*m, m in {1,3,5,7}
    long tot = 0;
    for (int i = 0; i < n_in; ++i) tot += in_sizes[i];
    const long N = (tot - 16384) / 512;
    const int  ms[4] = {1, 3, 5, 7};
    const float* xs[4]  = {nullptr, nullptr, nullptr, nullptr};
    const float* wsp[4] = {nullptr, nullptr, nullptr, nullptr};
    for (int i = 0; i < n_in; ++i) {
        const long s = in_sizes[i];
        for (int l = 0; l < 4; ++l) {
            if (s == N * 32 * ms[l])      xs[l]  = (const float*)d_in[i];
            else if (s == 1024L * ms[l])  wsp[l] = (const float*)d_in[i];
        }
    }
    const int n_tiles = (int)(N / TN);
    const int grid = 512;                 // 2 blocks/CU, persistent (16 tiles each)
    hipLaunchKernelGGL(eqlin, dim3(grid), dim3(NTH), 0, stream,
                       xs[0], xs[1], xs[2], xs[3],
                       wsp[0], wsp[1], wsp[2], wsp[3],
                       (float*)d_out, n_tiles);
}

// Round 4
// 210.187 us; speedup vs baseline: 1.4108x; 1.0326x over previous
//
#include <hip/hip_runtime.h>
#include <hip/hip_fp16.h>

// out[n,o,m](l) = sum_i W_l[o,i,m] * x_l[n,i,m];  N=262144, MULT=32, m_l in {1,3,5,7}.
// Memory-bound: 1.07GB @ ~6.3TB/s => ~170us floor.
//
// Round-4: 2 barriers/tile (was 4).
//  - W fragments hoisted to registers in prologue (tile-invariant) -> WT dead
//  - separate output overlay OC (33KB) disjoint from XT (40KB): phase A =
//    {staging XT + prefetch + stores of t-1 from OC}, phase B = {MFMA + overlay}
//  - issue order staging -> loads -> stores keeps next wait at vmcnt(8), no drain
// LDS 74KB -> 2 blocks/CU, 16 waves/CU (VGPR-capped anyway).

#define NTH 512
#define TN  32

typedef _Float16 f16x8 __attribute__((ext_vector_type(8)));
typedef float    f32x4 __attribute__((ext_vector_type(4)));

// LDS-only barrier: order ds ops, leave vmem in flight.
#define LGKM0_BAR() do { asm volatile("s_waitcnt lgkmcnt(0)" ::: "memory"); \
                         __builtin_amdgcn_s_barrier(); } while (0)

// W stage (prologue only): element e = o*(32*M_) + i*M_ + mi -> dst[(PB+mi)*1280 + o*40 + i]
template<int M_, int PB>
__device__ __forceinline__ void stageW(const float* __restrict__ src,
                                       __half* __restrict__ dst, int tid)
{
    #pragma unroll
    for (int it = 0; it < (256 * M_ + NTH - 1) / NTH; ++it) {
        const int f = tid + it * NTH;
        if (f < 256 * M_) {
            float4 v = ((const float4*)src)[f];
            const float vf[4] = {v.x, v.y, v.z, v.w};
            const int e0 = 4 * f;
            #pragma unroll
            for (int k = 0; k < 4; ++k) {
                const int e = e0 + k;
                const int o = e / (32 * M_);
                const int r = e - o * (32 * M_);
                const int i = r / M_, mi = r - i * M_;
                dst[(PB + mi) * 1280 + o * 40 + i] = __float2half(vf[k]);
            }
        }
    }
}

template<int M_, int PB>
__device__ __forceinline__ void mkoff(int tloc, int* offk)
{
    const int e0    = 4 * tloc;
    const int nodel = e0 / (32 * M_);
    const int r0    = e0 - nodel * (32 * M_);
    #pragma unroll
    for (int k = 0; k < 4; ++k) {
        const int ii = (r0 + k) / M_, mi = (r0 + k) - ii * M_;
        offk[k] = (PB + mi) * 1280 + nodel * 40 + ii;
    }
}

__device__ __forceinline__ void plane_info(int p, int& Mm, int& BASE, int& MI)
{
    if (p == 0)     { Mm = 1; BASE = 0;   MI = 0;     }
    else if (p < 4) { Mm = 3; BASE = 32;  MI = p - 1; }
    else if (p < 9) { Mm = 5; BASE = 128; MI = p - 4; }
    else            { Mm = 7; BASE = 288; MI = p - 9; }
}

__global__ __launch_bounds__(NTH, 4) void eqlin(
    const float* __restrict__ x0, const float* __restrict__ x1,
    const float* __restrict__ x2, const float* __restrict__ x3,
    const float* __restrict__ w0, const float* __restrict__ w1,
    const float* __restrict__ w2, const float* __restrict__ w3,
    float* __restrict__ out, int n_tiles)
{
    __shared__ __align__(16) __half XT[20480];   // 40KB: x planes (W staging in prologue)
    __shared__ __align__(16) __half OC[16640];   // 33KB: output overlay, node-stride 520
    const int tid  = threadIdx.x;
    const int wave = tid >> 6;
    const int lane = tid & 63;

    // ---- staging groups: [0,32)->x0, [32,128)->x1, [128,288)->x2, [288,512)->x3
    int thrg, Mg, offk[4];
    const float* xb;
    bool isM1 = false;
    if (tid < 32)       { thrg = 32;  Mg = 1; xb = x0; mkoff<1, 0>(tid,       offk); isM1 = true; }
    else if (tid < 128) { thrg = 96;  Mg = 3; xb = x1; mkoff<3, 1>(tid - 32,  offk); }
    else if (tid < 288) { thrg = 160; Mg = 5; xb = x2; mkoff<5, 4>(tid - 128, offk); }
    else                { thrg = 224; Mg = 7; xb = x3; mkoff<7, 9>(tid - 288, offk); }
    const int  tloc    = (tid < 32) ? tid : (tid < 128) ? tid - 32 : (tid < 288) ? tid - 128 : tid - 288;
    const long jstride = 4L * thrg;
    const long tstride = (long)gridDim.x * 1024L * Mg;

    // ---- prologue: prefetch tile blockIdx.x (overlaps W staging)
    const float* srcp = xb + (long)blockIdx.x * (1024L * Mg) + 4 * tloc;
    float4 pf[8];
    #pragma unroll
    for (int j = 0; j < 8; ++j)
        pf[j] = *(const float4*)(srcp + j * jstride);

    // ---- stage W into XT, hoist this wave's fragments to registers, free XT
    stageW<1, 0>(w0, XT, tid);
    stageW<3, 1>(w1, XT, tid);
    stageW<5, 4>(w2, XT, tid);
    stageW<7, 9>(w3, XT, tid);

    const int lrow = lane & 15;          // A row / B col / C col
    const int lk8  = (lane >> 4) * 8;    // k-chunk (halves)
    const int crow = (lane >> 4) * 4;    // C row base

    LGKM0_BAR();                         // W staged
    f16x8 Wf[2][2];
    {
        const __half* wb = XT + (wave * 2) * 1280 + lrow * 40 + lk8;
        Wf[0][0] = *(const f16x8*)wb;
        Wf[0][1] = *(const f16x8*)(wb + 640);
        Wf[1][0] = *(const f16x8*)(wb + 1280);
        Wf[1][1] = *(const f16x8*)(wb + 1920);
    }
    LGKM0_BAR();                         // all frag reads done; XT reusable

    int Mm0, BASE0, MI0, Mm1, BASE1, MI1;
    plane_info(wave * 2,     Mm0, BASE0, MI0);
    plane_info(wave * 2 + 1, Mm1, BASE1, MI1);

    long prev_node0 = -1;
    for (int t = blockIdx.x; t < n_tiles; t += gridDim.x) {
        const long node0 = (long)t * TN;

        // ======== phase A: staging + prefetch + stores of prev ========
        #pragma unroll
        for (int j = 0; j < 8; ++j) {
            const float4 v = pf[j];
            const int jb = j * 160;                  // +4 nodes per j
            if (isM1) {
                __half2* p = (__half2*)&XT[offk[0] + jb];
                p[0] = __floats2half2_rn(v.x, v.y);
                p[1] = __floats2half2_rn(v.z, v.w);
            } else {
                XT[offk[0] + jb] = __float2half(v.x);
                XT[offk[1] + jb] = __float2half(v.y);
                XT[offk[2] + jb] = __float2half(v.z);
                XT[offk[3] + jb] = __float2half(v.w);
            }
        }
        if (t + (long)gridDim.x < n_tiles) {         // prefetch (older than stores)
            srcp += tstride;
            #pragma unroll
            for (int j = 0; j < 8; ++j)
                pf[j] = *(const float4*)(srcp + j * jstride);
        }
        if (prev_node0 >= 0) {                       // stores of tile t-1 from OC
            float* dst = out + prev_node0 * 512;
            #pragma unroll
            for (int it = 0; it < 4; ++it) {
                const int d0   = 8 * tid + 4096 * it;
                const int node = d0 >> 9, col = d0 & 511;
                uint4 h8 = *(const uint4*)(OC + node * 520 + col);
                const __half2* hp = (const __half2*)&h8;
                float2 f0 = __half22float2(hp[0]);
                float2 f1 = __half22float2(hp[1]);
                float2 f2 = __half22float2(hp[2]);
                float2 f3 = __half22float2(hp[3]);
                *(float4*)(dst + d0)     = make_float4(f0.x, f0.y, f1.x, f1.y);
                *(float4*)(dst + d0 + 4) = make_float4(f2.x, f2.y, f3.x, f3.y);
            }
        }

        LGKM0_BAR();   // XT staged visible; OC reads done

        // ======== phase B: MFMA + overlay ========
        f32x4 acc[2][2][2] = {};         // [pl][nh][oh]
        #pragma unroll
        for (int pl = 0; pl < 2; ++pl) {
            const int plane = wave * 2 + pl;
            const __half* xp = XT + plane * 1280 + lrow * 40 + lk8;
            f16x8 A0 = *(const f16x8*)xp;
            f16x8 A1 = *(const f16x8*)(xp + 640);    // +16 nodes
            acc[pl][0][0] = __builtin_amdgcn_mfma_f32_16x16x32_f16(A0, Wf[pl][0], acc[pl][0][0], 0, 0, 0);
            acc[pl][0][1] = __builtin_amdgcn_mfma_f32_16x16x32_f16(A0, Wf[pl][1], acc[pl][0][1], 0, 0, 0);
            acc[pl][1][0] = __builtin_amdgcn_mfma_f32_16x16x32_f16(A1, Wf[pl][0], acc[pl][1][0], 0, 0, 0);
            acc[pl][1][1] = __builtin_amdgcn_mfma_f32_16x16x32_f16(A1, Wf[pl][1], acc[pl][1][1], 0, 0, 0);
        }
        #pragma unroll
        for (int pl = 0; pl < 2; ++pl) {
            const int Mm   = pl ? Mm1   : Mm0;
            const int BASE = pl ? BASE1 : BASE0;
            const int MI   = pl ? MI1   : MI0;
            #pragma unroll
            for (int nh = 0; nh < 2; ++nh)
            #pragma unroll
            for (int oh = 0; oh < 2; ++oh) {
                const int o     = oh * 16 + lrow;
                const int colb  = BASE + o * Mm + MI;
                const int nodeb = nh * 16 + crow;
                #pragma unroll
                for (int r = 0; r < 4; ++r)
                    OC[(nodeb + r) * 520 + colb] = __float2half(acc[pl][nh][oh][r]);
            }
        }

        LGKM0_BAR();   // MFMA's XT reads done; OC writes visible
        prev_node0 = node0;
    }

    // ---- epilogue: store last tile
    if (prev_node0 >= 0) {
        float* dst = out + prev_node0 * 512;
        #pragma unroll
        for (int it = 0; it < 4; ++it) {
            const int d0   = 8 * tid + 4096 * it;
            const int node = d0 >> 9, col = d0 & 511;
            uint4 h8 = *(const uint4*)(OC + node * 520 + col);
            const __half2* hp = (const __half2*)&h8;
            float2 f0 = __half22float2(hp[0]);
            float2 f1 = __half22float2(hp[1]);
            float2 f2 = __half22float2(hp[2]);
            float2 f3 = __half22float2(hp[3]);
            *(float4*)(dst + d0)     = make_float4(f0.x, f0.y, f1.x, f1.y);
            *(float4*)(dst + d0 + 4) = make_float4(f2.x, f2.y, f3.x, f3.y);
        }
    }
}

extern "C" void kernel_launch(void* const* d_in, const int* in_sizes, int n_in,
                              void* d_out, int out_size, void* d_ws, size_t ws_size,
                              hipStream_t stream)
{
    // Identify pointers by size: x_l = N*32*m, W_l = 1024*m, m in {1,3,5,7}
    long tot = 0;
    for (int i = 0; i < n_in; ++i) tot += in_sizes[i];
    const long N = (tot - 16384) / 512;
    const int  ms[4] = {1, 3, 5, 7};
    const float* xs[4]  = {nullptr, nullptr, nullptr, nullptr};
    const float* wsp[4] = {nullptr, nullptr, nullptr, nullptr};
    for (int i = 0; i < n_in; ++i) {
        const long s = in_sizes[i];
        for (int l = 0; l < 4; ++l) {
            if (s == N * 32 * ms[l])      xs[l]  = (const float*)d_in[i];
            else if (s == 1024L * ms[l])  wsp[l] = (const float*)d_in[i];
        }
    }
    const int n_tiles = (int)(N / TN);
    const int grid = 512;                 // 2 blocks/CU, persistent (16 tiles each)
    hipLaunchKernelGGL(eqlin, dim3(grid), dim3(NTH), 0, stream,
                       xs[0], xs[1], xs[2], xs[3],
                       wsp[0], wsp[1], wsp[2], wsp[3],
                       (float*)d_out, n_tiles);
}